// Round 1
// baseline (1439.416 us; speedup 1.0000x reference)
//
#include <hip/hip_runtime.h>
#include <hip/hip_bf16.h>

typedef __attribute__((ext_vector_type(8))) short short8;
typedef __attribute__((ext_vector_type(4))) float f32x4;

__device__ __forceinline__ unsigned short f2bf(float f) {
    unsigned u = __builtin_bit_cast(unsigned, f);
    u += 0x7fffu + ((u >> 16) & 1u);
    return (unsigned short)(u >> 16);
}

// ---------------------------------------------------------------------------
// K1: convert W (f32 [128][256] row-major, torch (out, 2*in)) to bf16 bits
// ---------------------------------------------------------------------------
__global__ void wconv_kernel(const float* __restrict__ W,
                             unsigned short* __restrict__ Wb, int n) {
    int i = blockIdx.x * blockDim.x + threadIdx.x;
    if (i < n) Wb[i] = f2bf(W[i]);
}

// ---------------------------------------------------------------------------
// K2: edge scatter. One edge per 32 lanes (2 edges/wave/iter).
// Each lane: float4 of the src row -> 4 returnless f32 atomics into summed.
// summed aliases d_out (zeroed beforehand).
// ---------------------------------------------------------------------------
__global__ void scatter_kernel(const float* __restrict__ x,
                               const int* __restrict__ src,
                               const int* __restrict__ dst,
                               float* summed,
                               unsigned* deg,
                               int E) {
    int tid   = blockIdx.x * blockDim.x + threadIdx.x;
    int lane  = tid & 63;
    int wave  = tid >> 6;
    int nwave = (gridDim.x * blockDim.x) >> 6;
    int half  = lane >> 5;   // which edge of the pair
    int qlane = lane & 31;   // 0..31 -> float4 index within the 128-f32 row

    for (int base = wave * 2; base < E; base += nwave * 2) {
        int e = base + half;
        if (e < E) {
            int s = src[e];
            int d = dst[e];
            const float4* xr = (const float4*)(x + (size_t)s * 128);
            float4 v = xr[qlane];
            float* srow = summed + (size_t)d * 128 + (size_t)qlane * 4;
            unsafeAtomicAdd(srow + 0, v.x);
            unsafeAtomicAdd(srow + 1, v.y);
            unsafeAtomicAdd(srow + 2, v.z);
            unsafeAtomicAdd(srow + 3, v.w);
            if (qlane == 0) atomicAdd(deg + d, 1u);
        }
    }
}

// ---------------------------------------------------------------------------
// K3: fused mean + concat + GEMM + ReLU.
// out[v][o] = relu( sum_k h[v][k] * W[o][k] ),  h = [x(128) | summed/deg(128)]
// Tile: block = 4 waves, 64 rows; wave -> 16 rows x 128 cols via
// 8 col-tiles x 8 K-steps of mfma_f32_16x16x32_bf16.
// A frag: lane holds h[row = l&15][k = ks*32 + (l>>4)*8 + j]
// B frag: lane holds Wt[k][col = l&15]  = Wb[(ct*16 + (l&15))*256 + k...]
// C/D   : col = l&15, row = (l>>4)*4 + r   [guide §3, m89-verified]
// Reads its own 16-row window of `summed` (== out) before overwriting.
// ---------------------------------------------------------------------------
__global__ __launch_bounds__(256) void gemm_kernel(const float* __restrict__ x,
                                                   const float* summed,
                                                   const unsigned* __restrict__ deg,
                                                   const unsigned short* __restrict__ Wb,
                                                   float* out, int N) {
    int lane = threadIdx.x & 63;
    int wave = threadIdx.x >> 6;
    int v0   = blockIdx.x * 64 + wave * 16;
    int arow = lane & 15;
    int kgrp = lane >> 4;          // 0..3
    int row  = v0 + arow;
    bool rok = row < N;

    float inv = 1.0f;
    if (rok) {
        unsigned d = deg[row];
        inv = (d > 0u) ? (1.0f / (float)d) : 1.0f;
    }

    short8 afrag[8];
#pragma unroll
    for (int ks = 0; ks < 4; ++ks) {           // x half: k in [0,128)
        short8 a = {};
        if (rok) {
            const float4* p = (const float4*)(x + (size_t)row * 128 + ks * 32 + kgrp * 8);
            float4 lo = p[0], hi = p[1];
            a[0] = (short)f2bf(lo.x); a[1] = (short)f2bf(lo.y);
            a[2] = (short)f2bf(lo.z); a[3] = (short)f2bf(lo.w);
            a[4] = (short)f2bf(hi.x); a[5] = (short)f2bf(hi.y);
            a[6] = (short)f2bf(hi.z); a[7] = (short)f2bf(hi.w);
        }
        afrag[ks] = a;
    }
#pragma unroll
    for (int ks = 0; ks < 4; ++ks) {           // agg half: k in [128,256)
        short8 a = {};
        if (rok) {
            const float4* p = (const float4*)(summed + (size_t)row * 128 + ks * 32 + kgrp * 8);
            float4 lo = p[0], hi = p[1];
            a[0] = (short)f2bf(lo.x * inv); a[1] = (short)f2bf(lo.y * inv);
            a[2] = (short)f2bf(lo.z * inv); a[3] = (short)f2bf(lo.w * inv);
            a[4] = (short)f2bf(hi.x * inv); a[5] = (short)f2bf(hi.y * inv);
            a[6] = (short)f2bf(hi.z * inv); a[7] = (short)f2bf(hi.w * inv);
        }
        afrag[4 + ks] = a;
    }

    f32x4 acc[8];
#pragma unroll
    for (int ct = 0; ct < 8; ++ct) acc[ct] = (f32x4){0.f, 0.f, 0.f, 0.f};

#pragma unroll
    for (int ks = 0; ks < 8; ++ks) {
        short8 a = afrag[ks];
#pragma unroll
        for (int ct = 0; ct < 8; ++ct) {
            const short8* bp =
                (const short8*)(Wb + ((size_t)(ct * 16 + arow) * 256 + ks * 32 + kgrp * 8));
            acc[ct] = __builtin_amdgcn_mfma_f32_16x16x32_bf16(a, *bp, acc[ct], 0, 0, 0);
        }
    }

#pragma unroll
    for (int ct = 0; ct < 8; ++ct) {
#pragma unroll
        for (int r = 0; r < 4; ++r) {
            int orow = v0 + kgrp * 4 + r;
            if (orow < N) {
                float val = acc[ct][r];
                out[(size_t)orow * 128 + ct * 16 + arow] = fmaxf(val, 0.0f);
            }
        }
    }
}

// ---------------------------------------------------------------------------
extern "C" void kernel_launch(void* const* d_in, const int* in_sizes, int n_in,
                              void* d_out, int out_size, void* d_ws, size_t ws_size,
                              hipStream_t stream) {
    const float* x  = (const float*)d_in[0];
    const int* src  = (const int*)d_in[1];
    const int* dst  = (const int*)d_in[2];
    const float* W  = (const float*)d_in[4];

    int N = in_sizes[0] / 128;
    int E = in_sizes[1];

    float* out = (float*)d_out;            // doubles as the f32 `summed` accumulator
    unsigned* deg = (unsigned*)d_ws;
    size_t degBytes = (((size_t)N * 4) + 255) & ~(size_t)255;
    unsigned short* Wb = (unsigned short*)((char*)d_ws + degBytes);

    hipMemsetAsync(d_out, 0, (size_t)out_size * sizeof(float), stream);
    hipMemsetAsync(deg, 0, (size_t)N * sizeof(unsigned), stream);

    wconv_kernel<<<(128 * 256 + 255) / 256, 256, 0, stream>>>(W, Wb, 128 * 256);
    scatter_kernel<<<2048, 256, 0, stream>>>(x, src, dst, out, deg, E);
    gemm_kernel<<<(N + 63) / 64, 256, 0, stream>>>(x, out, deg, Wb, out, N);
}

// Round 2
// 200.387 us; speedup vs baseline: 7.1832x; 7.1832x over previous
//
#include <hip/hip_runtime.h>
#include <hip/hip_bf16.h>

typedef __attribute__((ext_vector_type(8))) short short8;
typedef __attribute__((ext_vector_type(4))) float f32x4;

__device__ __forceinline__ unsigned short f2bf(float f) {
    unsigned u = __builtin_bit_cast(unsigned, f);
    u += 0x7fffu + ((u >> 16) & 1u);
    return (unsigned short)(u >> 16);
}

// ---------------------------------------------------------------------------
// K1: W (f32 [128][256]) -> bf16 bits
// ---------------------------------------------------------------------------
__global__ void wconv_kernel(const float* __restrict__ W,
                             unsigned short* __restrict__ Wb, int n) {
    int i = blockIdx.x * blockDim.x + threadIdx.x;
    if (i < n) Wb[i] = f2bf(W[i]);
}

// ---------------------------------------------------------------------------
// K2: degree count (800k int atomics — cheap vs 102.4M f32 atomics)
// ---------------------------------------------------------------------------
__global__ void count_kernel(const int* __restrict__ dst, unsigned* deg, int E) {
    int e = blockIdx.x * blockDim.x + threadIdx.x;
    if (e < E) atomicAdd(deg + dst[e], 1u);
}

// ---------------------------------------------------------------------------
// K3a: per-block inclusive scan of deg -> block-exclusive rowptr + block sums
// ---------------------------------------------------------------------------
__global__ void scan1_kernel(const unsigned* __restrict__ deg,
                             unsigned* __restrict__ rowptr,
                             unsigned* __restrict__ bsum, int N) {
    __shared__ unsigned s[256];
    int i = blockIdx.x * 256 + threadIdx.x;
    unsigned v = (i < N) ? deg[i] : 0u;
    s[threadIdx.x] = v;
    __syncthreads();
#pragma unroll
    for (int off = 1; off < 256; off <<= 1) {
        unsigned t = (threadIdx.x >= off) ? s[threadIdx.x - off] : 0u;
        __syncthreads();
        s[threadIdx.x] += t;
        __syncthreads();
    }
    if (i < N) rowptr[i] = s[threadIdx.x] - v;   // exclusive within block
    if (threadIdx.x == 255) bsum[blockIdx.x] = s[255];
}

// ---------------------------------------------------------------------------
// K3b: single-block exclusive scan of block sums (nb <= 256)
// ---------------------------------------------------------------------------
__global__ void scan2_kernel(unsigned* bsum, int nb) {
    __shared__ unsigned s[256];
    unsigned v = (threadIdx.x < (unsigned)nb) ? bsum[threadIdx.x] : 0u;
    s[threadIdx.x] = v;
    __syncthreads();
#pragma unroll
    for (int off = 1; off < 256; off <<= 1) {
        unsigned t = (threadIdx.x >= off) ? s[threadIdx.x - off] : 0u;
        __syncthreads();
        s[threadIdx.x] += t;
        __syncthreads();
    }
    bsum[threadIdx.x] = s[threadIdx.x] - v;      // exclusive
}

// ---------------------------------------------------------------------------
// K3c: add block offsets; set rowptr[N] = E
// ---------------------------------------------------------------------------
__global__ void scan3_kernel(unsigned* rowptr, const unsigned* __restrict__ bsum,
                             int N, int E) {
    int i = blockIdx.x * blockDim.x + threadIdx.x;
    if (i < N) rowptr[i] += bsum[i >> 8];
    if (i == N) rowptr[N] = (unsigned)E;
}

// ---------------------------------------------------------------------------
// K4: bucket-fill edge list: eidx[rowptr[dst]+pos] = src
// ---------------------------------------------------------------------------
__global__ void fill_kernel(const int* __restrict__ src,
                            const int* __restrict__ dst,
                            const unsigned* __restrict__ rowptr,
                            unsigned* cursor, int* __restrict__ eidx, int E) {
    int e = blockIdx.x * blockDim.x + threadIdx.x;
    if (e < E) {
        int d = dst[e];
        unsigned pos = atomicAdd(cursor + d, 1u);
        eidx[rowptr[d] + pos] = src[e];
    }
}

// ---------------------------------------------------------------------------
// K5: gather-sum. One wave per node; half-wave (32 lanes x float4) per edge,
// 2 edges/iter. x is L3-resident -> cache-BW gather, zero atomics.
// Writes full rows of `summed` (aliases d_out) -> no memset needed.
// ---------------------------------------------------------------------------
__global__ __launch_bounds__(256) void gather_kernel(const float* __restrict__ x,
                                                     const int* __restrict__ eidx,
                                                     const unsigned* __restrict__ rowptr,
                                                     float* __restrict__ summed, int N) {
    int tid  = blockIdx.x * blockDim.x + threadIdx.x;
    int wave = tid >> 6;
    int lane = tid & 63;
    if (wave >= N) return;
    int half = lane >> 5;
    int q    = lane & 31;

    unsigned beg = rowptr[wave], end = rowptr[wave + 1];
    f32x4 acc = {0.f, 0.f, 0.f, 0.f};
    for (unsigned e = beg + half; e < end; e += 2) {
        int s = eidx[e];
        const f32x4* p = (const f32x4*)(x + (size_t)s * 128);
        f32x4 v = p[q];
        acc.x += v.x; acc.y += v.y; acc.z += v.z; acc.w += v.w;
    }
    acc.x += __shfl_xor(acc.x, 32);
    acc.y += __shfl_xor(acc.y, 32);
    acc.z += __shfl_xor(acc.z, 32);
    acc.w += __shfl_xor(acc.w, 32);
    if (half == 0) {
        ((f32x4*)(summed + (size_t)wave * 128))[q] = acc;
    }
}

// ---------------------------------------------------------------------------
// K6: fused mean + concat + GEMM + ReLU (unchanged from round 1).
// ---------------------------------------------------------------------------
__global__ __launch_bounds__(256) void gemm_kernel(const float* __restrict__ x,
                                                   const float* summed,
                                                   const unsigned* __restrict__ deg,
                                                   const unsigned short* __restrict__ Wb,
                                                   float* out, int N) {
    int lane = threadIdx.x & 63;
    int wave = threadIdx.x >> 6;
    int v0   = blockIdx.x * 64 + wave * 16;
    int arow = lane & 15;
    int kgrp = lane >> 4;
    int row  = v0 + arow;
    bool rok = row < N;

    float inv = 1.0f;
    if (rok) {
        unsigned d = deg[row];
        inv = (d > 0u) ? (1.0f / (float)d) : 1.0f;
    }

    short8 afrag[8];
#pragma unroll
    for (int ks = 0; ks < 4; ++ks) {
        short8 a = {};
        if (rok) {
            const float4* p = (const float4*)(x + (size_t)row * 128 + ks * 32 + kgrp * 8);
            float4 lo = p[0], hi = p[1];
            a[0] = (short)f2bf(lo.x); a[1] = (short)f2bf(lo.y);
            a[2] = (short)f2bf(lo.z); a[3] = (short)f2bf(lo.w);
            a[4] = (short)f2bf(hi.x); a[5] = (short)f2bf(hi.y);
            a[6] = (short)f2bf(hi.z); a[7] = (short)f2bf(hi.w);
        }
        afrag[ks] = a;
    }
#pragma unroll
    for (int ks = 0; ks < 4; ++ks) {
        short8 a = {};
        if (rok) {
            const float4* p = (const float4*)(summed + (size_t)row * 128 + ks * 32 + kgrp * 8);
            float4 lo = p[0], hi = p[1];
            a[0] = (short)f2bf(lo.x * inv); a[1] = (short)f2bf(lo.y * inv);
            a[2] = (short)f2bf(lo.z * inv); a[3] = (short)f2bf(lo.w * inv);
            a[4] = (short)f2bf(hi.x * inv); a[5] = (short)f2bf(hi.y * inv);
            a[6] = (short)f2bf(hi.z * inv); a[7] = (short)f2bf(hi.w * inv);
        }
        afrag[4 + ks] = a;
    }

    f32x4 acc[8];
#pragma unroll
    for (int ct = 0; ct < 8; ++ct) acc[ct] = (f32x4){0.f, 0.f, 0.f, 0.f};

#pragma unroll
    for (int ks = 0; ks < 8; ++ks) {
        short8 a = afrag[ks];
#pragma unroll
        for (int ct = 0; ct < 8; ++ct) {
            const short8* bp =
                (const short8*)(Wb + ((size_t)(ct * 16 + arow) * 256 + ks * 32 + kgrp * 8));
            acc[ct] = __builtin_amdgcn_mfma_f32_16x16x32_bf16(a, *bp, acc[ct], 0, 0, 0);
        }
    }

#pragma unroll
    for (int ct = 0; ct < 8; ++ct) {
#pragma unroll
        for (int r = 0; r < 4; ++r) {
            int orow = v0 + kgrp * 4 + r;
            if (orow < N) {
                float val = acc[ct][r];
                out[(size_t)orow * 128 + ct * 16 + arow] = fmaxf(val, 0.0f);
            }
        }
    }
}

// ---------------------------------------------------------------------------
extern "C" void kernel_launch(void* const* d_in, const int* in_sizes, int n_in,
                              void* d_out, int out_size, void* d_ws, size_t ws_size,
                              hipStream_t stream) {
    const float* x  = (const float*)d_in[0];
    const int* src  = (const int*)d_in[1];
    const int* dst  = (const int*)d_in[2];
    const float* W  = (const float*)d_in[4];

    int N = in_sizes[0] / 128;
    int E = in_sizes[1];

    float* out = (float*)d_out;  // doubles as f32 `summed`

    // workspace layout (256B-aligned chunks)
    char* ws = (char*)d_ws;
    size_t o = 0;
    auto carve = [&](size_t bytes) {
        char* p = ws + o;
        o += (bytes + 255) & ~(size_t)255;
        return p;
    };
    unsigned* deg     = (unsigned*)carve((size_t)N * 4);
    unsigned* rowptr  = (unsigned*)carve((size_t)(N + 1) * 4);
    unsigned* cursor  = (unsigned*)carve((size_t)N * 4);
    unsigned* bsum    = (unsigned*)carve(256 * 4);
    int* eidx         = (int*)carve((size_t)E * 4);
    unsigned short* Wb = (unsigned short*)carve(128 * 256 * 2);

    hipMemsetAsync(deg, 0, (size_t)N * sizeof(unsigned), stream);
    hipMemsetAsync(cursor, 0, (size_t)N * sizeof(unsigned), stream);

    int nb = (N + 255) / 256;                     // 196 <= 256

    wconv_kernel<<<(128 * 256 + 255) / 256, 256, 0, stream>>>(W, Wb, 128 * 256);
    count_kernel<<<(E + 255) / 256, 256, 0, stream>>>(dst, deg, E);
    scan1_kernel<<<nb, 256, 0, stream>>>(deg, rowptr, bsum, N);
    scan2_kernel<<<1, 256, 0, stream>>>(bsum, nb);
    scan3_kernel<<<(N + 256) / 256, 256, 0, stream>>>(rowptr, bsum, N, E);
    fill_kernel<<<(E + 255) / 256, 256, 0, stream>>>(src, dst, rowptr, cursor, eidx, E);
    gather_kernel<<<(N * 64 + 255) / 256, 256, 0, stream>>>(x, eidx, rowptr, out, N);
    gemm_kernel<<<(N + 63) / 64, 256, 0, stream>>>(x, out, deg, Wb, out, N);
}